// Round 2
// baseline (1357.500 us; speedup 1.0000x reference)
//
#include <hip/hip_runtime.h>

#define DIM 128

static inline size_t align256(size_t x) { return (x + 255) & ~(size_t)255; }

// ---------------- degree counting ----------------
__global__ void k_deg(const int* __restrict__ src, const int* __restrict__ dst,
                      int* __restrict__ dout, int* __restrict__ din, int E) {
  int i = blockIdx.x * blockDim.x + threadIdx.x;
  int st = gridDim.x * blockDim.x;
  for (; i < E; i += st) {
    atomicAdd(&dout[src[i]], 1);
    atomicAdd(&din[dst[i]], 1);
  }
}

// ---------------- single-block exclusive scan (row_ptr + cursor init) ----------------
__global__ __launch_bounds__(1024) void k_scan(const int* __restrict__ cnt,
                                               int* __restrict__ rp,
                                               int* __restrict__ cur, int N) {
  __shared__ int wsh[16];
  __shared__ int carry_s;
  int t = threadIdx.x, lane = t & 63, wid = t >> 6;
  if (t == 0) carry_s = 0;
  __syncthreads();
  for (int base = 0; base < N; base += 1024) {
    int idx = base + t;
    int x = (idx < N) ? cnt[idx] : 0;
    int v = x;
#pragma unroll
    for (int d = 1; d < 64; d <<= 1) {
      int u = __shfl_up(v, d, 64);
      if (lane >= d) v += u;
    }
    if (lane == 63) wsh[wid] = v;
    __syncthreads();
    if (wid == 0) {
      int wv = (lane < 16) ? wsh[lane] : 0;
#pragma unroll
      for (int d = 1; d < 16; d <<= 1) {
        int u = __shfl_up(wv, d, 64);
        if (lane >= d) wv += u;
      }
      if (lane < 16) wsh[lane] = wv;
    }
    __syncthreads();
    int woff = wid ? wsh[wid - 1] : 0;
    int incl = v + woff;
    int carry = carry_s;
    if (idx < N) {
      int e = carry + incl - x;
      rp[idx] = e;
      cur[idx] = e;
    }
    __syncthreads();
    if (t == 1023) carry_s = carry + incl;
    __syncthreads();
  }
  if (t == 0) rp[N] = carry_s;
}

// ---------------- CSR fill ----------------
__global__ void k_fill(const int* __restrict__ src, const int* __restrict__ dst,
                       int* __restrict__ cur, int* __restrict__ col, int E) {
  int i = blockIdx.x * blockDim.x + threadIdx.x;
  int st = gridDim.x * blockDim.x;
  for (; i < E; i += st) {
    int d = dst[i];
    int p = atomicAdd(&cur[d], 1);
    col[p] = src[i];
  }
}

// ---------------- m = (h * rsqrt(max(deg_out,1))) @ W  (wave per node) ----------------
__global__ __launch_bounds__(256) void k_gemm(const float* __restrict__ h,
                                              const float* __restrict__ W,
                                              const int* __restrict__ degout,
                                              float* __restrict__ m, int N) {
  __shared__ float Wl[DIM * DIM];
  for (int i = threadIdx.x; i < DIM * DIM; i += 256) Wl[i] = W[i];
  __syncthreads();
  int lane = threadIdx.x & 63, wid = threadIdx.x >> 6;
  int gw = blockIdx.x * 4 + wid, nw = gridDim.x * 4;
  for (int n = gw; n < N; n += nw) {
    float s = rsqrtf(fmaxf((float)degout[n], 1.0f));
    const float4* h4 = (const float4*)(h + (size_t)n * DIM);
    float ax = 0.f, ay = 0.f;
#pragma unroll 4
    for (int k4 = 0; k4 < 32; ++k4) {
      float4 hv = h4[k4];
      int k = k4 * 4;
      float2 w0 = *(const float2*)&Wl[(k + 0) * DIM + 2 * lane];
      float2 w1 = *(const float2*)&Wl[(k + 1) * DIM + 2 * lane];
      float2 w2 = *(const float2*)&Wl[(k + 2) * DIM + 2 * lane];
      float2 w3 = *(const float2*)&Wl[(k + 3) * DIM + 2 * lane];
      ax = fmaf(hv.x, w0.x, ax); ay = fmaf(hv.x, w0.y, ay);
      ax = fmaf(hv.y, w1.x, ax); ay = fmaf(hv.y, w1.y, ay);
      ax = fmaf(hv.z, w2.x, ax); ay = fmaf(hv.z, w2.y, ay);
      ax = fmaf(hv.w, w3.x, ax); ay = fmaf(hv.w, w3.y, ay);
    }
    float2 o; o.x = s * ax; o.y = s * ay;
    *(float2*)(m + (size_t)n * DIM + 2 * lane) = o;
  }
}

// ---------------- pull aggregation: z[n] = rsqrt(max(deg_in,1)) * sum_e m[col[e]] ----------------
__global__ __launch_bounds__(256) void k_pull(const float* __restrict__ m,
                                              const int* __restrict__ rp,
                                              const int* __restrict__ col,
                                              float* __restrict__ z, int N) {
  int lane = threadIdx.x & 63, wid = threadIdx.x >> 6;
  int gw = blockIdx.x * 4 + wid, nw = gridDim.x * 4;
  for (int n = gw; n < N; n += nw) {
    int b = rp[n], e = rp[n + 1];
    float ax = 0.f, ay = 0.f;
    for (int idx = b; idx < e; ++idx) {
      int s = col[idx];
      float2 v = *(const float2*)(m + (size_t)s * DIM + 2 * lane);
      ax += v.x; ay += v.y;
    }
    float sc = rsqrtf(fmaxf((float)(e - b), 1.0f));
    float2 o; o.x = ax * sc; o.y = ay * sc;
    *(float2*)(z + (size_t)n * DIM + 2 * lane) = o;
  }
}

// ---------------- attention scores: wsum[r] = sum_n tanh(z_r[n]@attW + b) . q ----------------
__global__ __launch_bounds__(256) void k_att(const float* __restrict__ z1,
                                             const float* __restrict__ z2,
                                             const float* __restrict__ attW,
                                             const float* __restrict__ attb,
                                             const float* __restrict__ attq,
                                             float* __restrict__ wsum, int N) {
  __shared__ float Wl[DIM * DIM];
  for (int i = threadIdx.x; i < DIM * DIM; i += 256) Wl[i] = attW[i];
  int lane = threadIdx.x & 63, wid = threadIdx.x >> 6;
  float b0 = attb[2 * lane], b1 = attb[2 * lane + 1];
  float q0 = attq[2 * lane], q1 = attq[2 * lane + 1];
  __syncthreads();
  int gw = blockIdx.x * 4 + wid, nw = gridDim.x * 4;
  float a1 = 0.f, a2 = 0.f;
  for (int n = gw; n < N; n += nw) {
    const float4* p1 = (const float4*)(z1 + (size_t)n * DIM);
    const float4* p2 = (const float4*)(z2 + (size_t)n * DIM);
    float c1x = 0, c1y = 0, c2x = 0, c2y = 0;
#pragma unroll 4
    for (int k4 = 0; k4 < 32; ++k4) {
      float4 u = p1[k4];
      float4 v = p2[k4];
      int k = k4 * 4;
      float2 w0 = *(const float2*)&Wl[(k + 0) * DIM + 2 * lane];
      float2 w1 = *(const float2*)&Wl[(k + 1) * DIM + 2 * lane];
      float2 w2 = *(const float2*)&Wl[(k + 2) * DIM + 2 * lane];
      float2 w3 = *(const float2*)&Wl[(k + 3) * DIM + 2 * lane];
      c1x = fmaf(u.x, w0.x, c1x); c1y = fmaf(u.x, w0.y, c1y);
      c2x = fmaf(v.x, w0.x, c2x); c2y = fmaf(v.x, w0.y, c2y);
      c1x = fmaf(u.y, w1.x, c1x); c1y = fmaf(u.y, w1.y, c1y);
      c2x = fmaf(v.y, w1.x, c2x); c2y = fmaf(v.y, w1.y, c2y);
      c1x = fmaf(u.z, w2.x, c1x); c1y = fmaf(u.z, w2.y, c1y);
      c2x = fmaf(v.z, w2.x, c2x); c2y = fmaf(v.z, w2.y, c2y);
      c1x = fmaf(u.w, w3.x, c1x); c1y = fmaf(u.w, w3.y, c1y);
      c2x = fmaf(v.w, w3.x, c2x); c2y = fmaf(v.w, w3.y, c2y);
    }
    a1 += tanhf(c1x + b0) * q0 + tanhf(c1y + b1) * q1;
    a2 += tanhf(c2x + b0) * q0 + tanhf(c2y + b1) * q1;
  }
#pragma unroll
  for (int off = 32; off; off >>= 1) {
    a1 += __shfl_down(a1, off, 64);
    a2 += __shfl_down(a2, off, 64);
  }
  __syncthreads();  // done reading Wl; reuse as scratch
  if (lane == 0) { Wl[wid] = a1; Wl[8 + wid] = a2; }
  __syncthreads();
  if (threadIdx.x == 0) {
    atomicAdd(&wsum[0], Wl[0] + Wl[1] + Wl[2] + Wl[3]);
    atomicAdd(&wsum[1], Wl[8] + Wl[9] + Wl[10] + Wl[11]);
  }
}

// ---------------- x = beta1*z1 + beta2*z2 (in place over z1) ----------------
__global__ void k_combine(float* __restrict__ x, const float* __restrict__ z2,
                          const float* __restrict__ wsum, float invN, int total4) {
  float w1 = wsum[0] * invN, w2 = wsum[1] * invN;
  float mx = fmaxf(w1, w2);
  float e1 = expf(w1 - mx), e2 = expf(w2 - mx);
  float inv = 1.f / (e1 + e2);
  float b1 = e1 * inv, b2 = e2 * inv;
  float4* x4 = (float4*)x;
  const float4* z4 = (const float4*)z2;
  int i = blockIdx.x * blockDim.x + threadIdx.x;
  int st = gridDim.x * blockDim.x;
  for (; i < total4; i += st) {
    float4 a = x4[i], b = z4[i];
    a.x = b1 * a.x + b2 * b.x;
    a.y = b1 * a.y + b2 * b.y;
    a.z = b1 * a.z + b2 * b.z;
    a.w = b1 * a.w + b2 * b.w;
    x4[i] = a;
  }
}

// ---------------- column sums / sumsq for BatchNorm ----------------
__global__ __launch_bounds__(128) void k_stats(const float* __restrict__ x,
                                               float* __restrict__ cs,
                                               float* __restrict__ cq, int N) {
  int d = threadIdx.x;
  float s = 0.f, q = 0.f;
  for (int n = blockIdx.x; n < N; n += gridDim.x) {
    float v = x[(size_t)n * DIM + d];
    s += v;
    q += v * v;
  }
  atomicAdd(&cs[d], s);
  atomicAdd(&cq[d], q);
}

// ---------------- BatchNorm + row L2 normalize (in place) ----------------
__global__ __launch_bounds__(128) void k_post(float* __restrict__ x,
                                              const float* __restrict__ cs,
                                              const float* __restrict__ cq,
                                              const float* __restrict__ gamma,
                                              const float* __restrict__ beta,
                                              float invN, int N) {
  int d = threadIdx.x, lane = d & 63, wid = d >> 6;
  __shared__ float red[2];
  float mu = cs[d] * invN;
  float var = cq[d] * invN - mu * mu;
  float istd = rsqrtf(var + 1e-5f);
  float g = gamma[d], bb = beta[d];
  for (int n = blockIdx.x; n < N; n += gridDim.x) {
    float v = x[(size_t)n * DIM + d];
    float y = fmaf((v - mu) * istd, g, bb);
    float p = y * y;
#pragma unroll
    for (int off = 32; off; off >>= 1) p += __shfl_down(p, off, 64);
    if (lane == 0) red[wid] = p;
    __syncthreads();
    float rs = red[0] + red[1];
    x[(size_t)n * DIM + d] = y * rsqrtf(rs + 1e-12f);
    __syncthreads();
  }
}

extern "C" void kernel_launch(void* const* d_in, const int* in_sizes, int n_in,
                              void* d_out, int out_size, void* d_ws, size_t ws_size,
                              hipStream_t stream) {
  const float* h_paper  = (const float*)d_in[0];
  const float* h_author = (const float*)d_in[1];
  const float* W_r1 = (const float*)d_in[2];
  const float* W_r2 = (const float*)d_in[3];
  const float* W_r3 = (const float*)d_in[4];
  const float* att_W = (const float*)d_in[5];
  const float* att_b = (const float*)d_in[6];
  const float* att_q = (const float*)d_in[7];
  const float* bn_g = (const float*)d_in[8];
  const float* bn_b = (const float*)d_in[9];
  const int* src_r1 = (const int*)d_in[10];
  const int* dst_r1 = (const int*)d_in[11];
  const int* src_r2 = (const int*)d_in[12];
  const int* dst_r2 = (const int*)d_in[13];
  const int* src_r3 = (const int*)d_in[14];
  const int* dst_r3 = (const int*)d_in[15];

  int NP = in_sizes[0] / DIM;
  int NA = in_sizes[1] / DIM;
  int E1 = in_sizes[10], E2 = in_sizes[12], E3 = in_sizes[14];
  int NMAX = NP > NA ? NP : NA;

  char* ws = (char*)d_ws;
  size_t off = 0;
  float* m_buf = (float*)(ws + off); off += align256((size_t)NMAX * DIM * 4);
  float* z2    = (float*)(ws + off); off += align256((size_t)NP * DIM * 4);
  int* col     = (int*)(ws + off);   off += align256(((size_t)E1 + E2 + E3) * 4);
  int* rp      = (int*)(ws + off);   off += align256((size_t)3 * (NMAX + 1) * 4);
  int* cur     = (int*)(ws + off);   off += align256((size_t)3 * NMAX * 4);
  size_t zoff = off;  // beginning of zero-initialized region
  int* din     = (int*)(ws + off);   off += (size_t)3 * NMAX * 4;
  int* dout    = (int*)(ws + off);   off += (size_t)3 * NMAX * 4;
  float* wsum  = (float*)(ws + off); off += 2 * 4;
  float* stats = (float*)(ws + off); off += 4 * DIM * 4;  // csum_p, csq_p, csum_a, csq_a
  size_t zbytes = off - zoff;

  float* xp = (float*)d_out;                       // papers (also z_p1 staging)
  float* xa = (float*)d_out + (size_t)NP * DIM;    // authors (also z_a1 staging)

  hipMemsetAsync(ws + zoff, 0, zbytes, stream);

  // degrees
  k_deg<<<1024, 256, 0, stream>>>(src_r1, dst_r1, dout + 0,        din + 0,        E1);
  k_deg<<<1024, 256, 0, stream>>>(src_r2, dst_r2, dout + NMAX,     din + NMAX,     E2);
  k_deg<<<1024, 256, 0, stream>>>(src_r3, dst_r3, dout + 2 * NMAX, din + 2 * NMAX, E3);

  // row_ptr scans (+cursor copies)
  k_scan<<<1, 1024, 0, stream>>>(din + 0,        rp + 0,              cur + 0,        NP);
  k_scan<<<1, 1024, 0, stream>>>(din + NMAX,     rp + (NMAX + 1),     cur + NMAX,     NP);
  k_scan<<<1, 1024, 0, stream>>>(din + 2 * NMAX, rp + 2 * (NMAX + 1), cur + 2 * NMAX, NA);

  // CSR fills
  k_fill<<<1024, 256, 0, stream>>>(src_r1, dst_r1, cur + 0,        col,                     E1);
  k_fill<<<1024, 256, 0, stream>>>(src_r2, dst_r2, cur + NMAX,     col + (size_t)E1,        E2);
  k_fill<<<1024, 256, 0, stream>>>(src_r3, dst_r3, cur + 2 * NMAX, col + (size_t)E1 + E2,   E3);

  // r1: author -> paper   (z_p1 staged directly in d_out paper region)
  k_gemm<<<512, 256, 0, stream>>>(h_author, W_r1, dout + 0, m_buf, NA);
  k_pull<<<2048, 256, 0, stream>>>(m_buf, rp + 0, col, xp, NP);
  // r2: paper -> paper    (z_p2 in workspace)
  k_gemm<<<512, 256, 0, stream>>>(h_paper, W_r2, dout + NMAX, m_buf, NP);
  k_pull<<<2048, 256, 0, stream>>>(m_buf, rp + (NMAX + 1), col + (size_t)E1, z2, NP);
  // r3: author -> author  (z_a1 staged directly in d_out author region; softmax over 1 rel == identity)
  k_gemm<<<512, 256, 0, stream>>>(h_author, W_r3, dout + 2 * NMAX, m_buf, NA);
  k_pull<<<2048, 256, 0, stream>>>(m_buf, rp + 2 * (NMAX + 1), col + (size_t)E1 + E2, xa, NA);

  // semantic attention for papers
  k_att<<<512, 256, 0, stream>>>(xp, z2, att_W, att_b, att_q, wsum, NP);
  k_combine<<<2048, 256, 0, stream>>>(xp, z2, wsum, 1.0f / (float)NP, NP * DIM / 4);

  // post: BatchNorm (train stats) + row L2
  k_stats<<<1024, 128, 0, stream>>>(xp, stats, stats + DIM, NP);
  k_post<<<2048, 128, 0, stream>>>(xp, stats, stats + DIM, bn_g, bn_b, 1.0f / (float)NP, NP);
  k_stats<<<1024, 128, 0, stream>>>(xa, stats + 2 * DIM, stats + 3 * DIM, NA);
  k_post<<<2048, 128, 0, stream>>>(xa, stats + 2 * DIM, stats + 3 * DIM, bn_g, bn_b, 1.0f / (float)NA, NA);
}

// Round 6
// 1108.853 us; speedup vs baseline: 1.2242x; 1.2242x over previous
//
#include <hip/hip_runtime.h>

#define DIM 128

static inline size_t align256(size_t x) { return (x + 255) & ~(size_t)255; }

// ---------------- degree counting, all 3 relations ----------------
__global__ void k_deg3(const int* __restrict__ s1, const int* __restrict__ d1, int E1,
                       const int* __restrict__ s2, const int* __restrict__ d2, int E2,
                       const int* __restrict__ s3, const int* __restrict__ d3, int E3,
                       int* __restrict__ dout, int* __restrict__ din, int NM) {
  int i = blockIdx.x * blockDim.x + threadIdx.x;
  int st = gridDim.x * blockDim.x;
  int ET = E1 + E2 + E3;
  for (; i < ET; i += st) {
    const int* sp; const int* dp; int j, r;
    if (i < E1) { r = 0; j = i; sp = s1; dp = d1; }
    else if (i < E1 + E2) { r = 1; j = i - E1; sp = s2; dp = d2; }
    else { r = 2; j = i - E1 - E2; sp = s3; dp = d3; }
    atomicAdd(&dout[r * NM + sp[j]], 1);
    atomicAdd(&din[r * NM + dp[j]], 1);
  }
}

// ---------------- multi-block scan over concatenated counts ----------------
// pass 1: per-block (2048 elems) totals
__global__ __launch_bounds__(256) void k_scan1(const int* __restrict__ cnt,
                                               int* __restrict__ part, int M) {
  __shared__ int wsh[4];
  int t = threadIdx.x;
  int base = blockIdx.x * 2048 + t * 8;
  int s = 0;
  if (base + 8 <= M) {
    const int4* p = (const int4*)(cnt + base);
    int4 a = p[0], b = p[1];
    s = a.x + a.y + a.z + a.w + b.x + b.y + b.z + b.w;
  } else {
    for (int j = 0; j < 8; ++j) { int idx = base + j; if (idx < M) s += cnt[idx]; }
  }
#pragma unroll
  for (int off = 32; off; off >>= 1) s += __shfl_down(s, off, 64);
  int lane = t & 63, wid = t >> 6;
  if (lane == 0) wsh[wid] = s;
  __syncthreads();
  if (t == 0) part[blockIdx.x] = wsh[0] + wsh[1] + wsh[2] + wsh[3];
}

// pass 2: single block exclusive-scans the partials (B <= 256), writes total to rp[M]
__global__ __launch_bounds__(256) void k_scan2(int* __restrict__ part, int B,
                                               int* __restrict__ rp, int M) {
  __shared__ int sh[256];
  int t = threadIdx.x;
  sh[t] = (t < B) ? part[t] : 0;
  __syncthreads();
  for (int off = 1; off < 256; off <<= 1) {
    int v = (t >= off) ? sh[t - off] : 0;
    __syncthreads();
    sh[t] += v;
    __syncthreads();
  }
  if (t < B) part[t] = t ? sh[t - 1] : 0;
  if (t == 0) rp[M] = sh[255];
}

// pass 3: re-scan chunks, add offsets, write rp + cur
__global__ __launch_bounds__(256) void k_scan3(const int* __restrict__ cnt,
                                               const int* __restrict__ part,
                                               int* __restrict__ rp,
                                               int* __restrict__ cur, int M) {
  __shared__ int wsh[4];
  int t = threadIdx.x, lane = t & 63, wid = t >> 6;
  int base = blockIdx.x * 2048 + t * 8;
  int v[8];
  if (base + 8 <= M) {
    const int4* p = (const int4*)(cnt + base);
    int4 a = p[0], b = p[1];
    v[0] = a.x; v[1] = a.y; v[2] = a.z; v[3] = a.w;
    v[4] = b.x; v[5] = b.y; v[6] = b.z; v[7] = b.w;
  } else {
    for (int j = 0; j < 8; ++j) { int idx = base + j; v[j] = (idx < M) ? cnt[idx] : 0; }
  }
  int ts = 0;
#pragma unroll
  for (int j = 0; j < 8; ++j) ts += v[j];
  int incl = ts;
#pragma unroll
  for (int d = 1; d < 64; d <<= 1) { int u = __shfl_up(incl, d, 64); if (lane >= d) incl += u; }
  if (lane == 63) wsh[wid] = incl;
  __syncthreads();
  int woff = 0;
  for (int w = 0; w < wid; ++w) woff += wsh[w];
  int run = part[blockIdx.x] + woff + incl - ts;
#pragma unroll
  for (int j = 0; j < 8; ++j) {
    int idx = base + j;
    if (idx < M) { rp[idx] = run; cur[idx] = run; }
    run += v[j];
  }
}

// ---------------- CSR fill, all 3 relations (global col positions) ----------------
__global__ void k_fill3(const int* __restrict__ s1, const int* __restrict__ d1, int E1,
                        const int* __restrict__ s2, const int* __restrict__ d2, int E2,
                        const int* __restrict__ s3, const int* __restrict__ d3, int E3,
                        int* __restrict__ cur, int* __restrict__ col, int NM) {
  int i = blockIdx.x * blockDim.x + threadIdx.x;
  int st = gridDim.x * blockDim.x;
  int ET = E1 + E2 + E3;
  for (; i < ET; i += st) {
    const int* sp; const int* dp; int j, r;
    if (i < E1) { r = 0; j = i; sp = s1; dp = d1; }
    else if (i < E1 + E2) { r = 1; j = i - E1; sp = s2; dp = d2; }
    else { r = 2; j = i - E1 - E2; sp = s3; dp = d3; }
    int p = atomicAdd(&cur[r * NM + dp[j]], 1);
    col[p] = sp[j];
  }
}

// ---------------- m = (h * rsqrt(max(deg_out,1))) @ W  (wave per node, 512 thr) ----------------
__global__ __launch_bounds__(512) void k_gemm(const float* __restrict__ h,
                                              const float* __restrict__ W,
                                              const int* __restrict__ degout,
                                              float* __restrict__ m, int N) {
  __shared__ float Wl[DIM * DIM];
  for (int i = threadIdx.x; i < DIM * DIM; i += 512) Wl[i] = W[i];
  __syncthreads();
  int lane = threadIdx.x & 63, wid = threadIdx.x >> 6;
  int gw = blockIdx.x * 8 + wid, nw = gridDim.x * 8;
  for (int n = gw; n < N; n += nw) {
    float s = rsqrtf(fmaxf((float)degout[n], 1.0f));
    const float4* h4 = (const float4*)(h + (size_t)n * DIM);
    float ax = 0.f, ay = 0.f;
#pragma unroll 4
    for (int k4 = 0; k4 < 32; ++k4) {
      float4 hv = h4[k4];
      int k = k4 * 4;
      float2 w0 = *(const float2*)&Wl[(k + 0) * DIM + 2 * lane];
      float2 w1 = *(const float2*)&Wl[(k + 1) * DIM + 2 * lane];
      float2 w2 = *(const float2*)&Wl[(k + 2) * DIM + 2 * lane];
      float2 w3 = *(const float2*)&Wl[(k + 3) * DIM + 2 * lane];
      ax = fmaf(hv.x, w0.x, ax); ay = fmaf(hv.x, w0.y, ay);
      ax = fmaf(hv.y, w1.x, ax); ay = fmaf(hv.y, w1.y, ay);
      ax = fmaf(hv.z, w2.x, ax); ay = fmaf(hv.z, w2.y, ay);
      ax = fmaf(hv.w, w3.x, ax); ay = fmaf(hv.w, w3.y, ay);
    }
    float2 o; o.x = s * ax; o.y = s * ay;
    *(float2*)(m + (size_t)n * DIM + 2 * lane) = o;
  }
}

// ---------------- pull aggregation ----------------
__global__ __launch_bounds__(256) void k_pull(const float* __restrict__ m,
                                              const int* __restrict__ rp,
                                              const int* __restrict__ col,
                                              float* __restrict__ z, int N) {
  int lane = threadIdx.x & 63, wid = threadIdx.x >> 6;
  int gw = blockIdx.x * 4 + wid, nw = gridDim.x * 4;
  for (int n = gw; n < N; n += nw) {
    int b = rp[n], e = rp[n + 1];
    float ax = 0.f, ay = 0.f;
    for (int idx = b; idx < e; ++idx) {
      int s = col[idx];
      float2 v = *(const float2*)(m + (size_t)s * DIM + 2 * lane);
      ax += v.x; ay += v.y;
    }
    float sc = rsqrtf(fmaxf((float)(e - b), 1.0f));
    float2 o; o.x = ax * sc; o.y = ay * sc;
    *(float2*)(z + (size_t)n * DIM + 2 * lane) = o;
  }
}

// ---------------- attention scores (512 thr) ----------------
__global__ __launch_bounds__(512) void k_att(const float* __restrict__ z1,
                                             const float* __restrict__ z2,
                                             const float* __restrict__ attW,
                                             const float* __restrict__ attb,
                                             const float* __restrict__ attq,
                                             float* __restrict__ wsum, int N) {
  __shared__ float Wl[DIM * DIM];
  for (int i = threadIdx.x; i < DIM * DIM; i += 512) Wl[i] = attW[i];
  int lane = threadIdx.x & 63, wid = threadIdx.x >> 6;
  float b0 = attb[2 * lane], b1 = attb[2 * lane + 1];
  float q0 = attq[2 * lane], q1 = attq[2 * lane + 1];
  __syncthreads();
  int gw = blockIdx.x * 8 + wid, nw = gridDim.x * 8;
  float a1 = 0.f, a2 = 0.f;
  for (int n = gw; n < N; n += nw) {
    const float4* p1 = (const float4*)(z1 + (size_t)n * DIM);
    const float4* p2 = (const float4*)(z2 + (size_t)n * DIM);
    float c1x = 0, c1y = 0, c2x = 0, c2y = 0;
#pragma unroll 4
    for (int k4 = 0; k4 < 32; ++k4) {
      float4 u = p1[k4];
      float4 v = p2[k4];
      int k = k4 * 4;
      float2 w0 = *(const float2*)&Wl[(k + 0) * DIM + 2 * lane];
      float2 w1 = *(const float2*)&Wl[(k + 1) * DIM + 2 * lane];
      float2 w2 = *(const float2*)&Wl[(k + 2) * DIM + 2 * lane];
      float2 w3 = *(const float2*)&Wl[(k + 3) * DIM + 2 * lane];
      c1x = fmaf(u.x, w0.x, c1x); c1y = fmaf(u.x, w0.y, c1y);
      c2x = fmaf(v.x, w0.x, c2x); c2y = fmaf(v.x, w0.y, c2y);
      c1x = fmaf(u.y, w1.x, c1x); c1y = fmaf(u.y, w1.y, c1y);
      c2x = fmaf(v.y, w1.x, c2x); c2y = fmaf(v.y, w1.y, c2y);
      c1x = fmaf(u.z, w2.x, c1x); c1y = fmaf(u.z, w2.y, c1y);
      c2x = fmaf(v.z, w2.x, c2x); c2y = fmaf(v.z, w2.y, c2y);
      c1x = fmaf(u.w, w3.x, c1x); c1y = fmaf(u.w, w3.y, c1y);
      c2x = fmaf(v.w, w3.x, c2x); c2y = fmaf(v.w, w3.y, c2y);
    }
    a1 += tanhf(c1x + b0) * q0 + tanhf(c1y + b1) * q1;
    a2 += tanhf(c2x + b0) * q0 + tanhf(c2y + b1) * q1;
  }
#pragma unroll
  for (int off = 32; off; off >>= 1) {
    a1 += __shfl_down(a1, off, 64);
    a2 += __shfl_down(a2, off, 64);
  }
  __syncthreads();  // done reading Wl; reuse as scratch
  if (lane == 0) { Wl[wid] = a1; Wl[8 + wid] = a2; }
  __syncthreads();
  if (threadIdx.x == 0) {
    float s1 = 0, s2 = 0;
    for (int w = 0; w < 8; ++w) { s1 += Wl[w]; s2 += Wl[8 + w]; }
    atomicAdd(&wsum[0], s1);
    atomicAdd(&wsum[1], s2);
  }
}

// ---------------- x = beta1*z1 + beta2*z2 (in place over z1) ----------------
__global__ void k_combine(float* __restrict__ x, const float* __restrict__ z2,
                          const float* __restrict__ wsum, float invN, int total4) {
  float w1 = wsum[0] * invN, w2 = wsum[1] * invN;
  float mx = fmaxf(w1, w2);
  float e1 = expf(w1 - mx), e2 = expf(w2 - mx);
  float inv = 1.f / (e1 + e2);
  float b1 = e1 * inv, b2 = e2 * inv;
  float4* x4 = (float4*)x;
  const float4* z4 = (const float4*)z2;
  int i = blockIdx.x * blockDim.x + threadIdx.x;
  int st = gridDim.x * blockDim.x;
  for (; i < total4; i += st) {
    float4 a = x4[i], b = z4[i];
    a.x = b1 * a.x + b2 * b.x;
    a.y = b1 * a.y + b2 * b.y;
    a.z = b1 * a.z + b2 * b.z;
    a.w = b1 * a.w + b2 * b.w;
    x4[i] = a;
  }
}

// ---------------- column stats for BOTH outputs ----------------
__global__ __launch_bounds__(128) void k_stats2(const float* __restrict__ xp,
                                                const float* __restrict__ xa,
                                                int NP, int NA, float* __restrict__ st) {
  int d = threadIdx.x;
  float sp = 0, qp = 0, sa = 0, qa = 0;
  for (int n = blockIdx.x; n < NP; n += gridDim.x) {
    float v = xp[(size_t)n * DIM + d]; sp += v; qp += v * v;
  }
  for (int n = blockIdx.x; n < NA; n += gridDim.x) {
    float v = xa[(size_t)n * DIM + d]; sa += v; qa += v * v;
  }
  atomicAdd(&st[d], sp);
  atomicAdd(&st[DIM + d], qp);
  atomicAdd(&st[2 * DIM + d], sa);
  atomicAdd(&st[3 * DIM + d], qa);
}

// ---------------- BatchNorm + row L2 normalize, wave per row, both outputs ----------------
__global__ __launch_bounds__(256) void k_post2(float* __restrict__ xp, float* __restrict__ xa,
                                               const float* __restrict__ st,
                                               const float* __restrict__ gamma,
                                               const float* __restrict__ beta,
                                               int NP, int NA) {
  int lane = threadIdx.x & 63;
  int wv = blockIdx.x * 4 + (threadIdx.x >> 6), nw = gridDim.x * 4;
  int d0 = 2 * lane, d1 = d0 + 1;
  {
    float invN = 1.f / (float)NP;
    float mu0 = st[d0] * invN, mu1 = st[d1] * invN;
    float g0 = gamma[d0] * rsqrtf(st[DIM + d0] * invN - mu0 * mu0 + 1e-5f);
    float g1 = gamma[d1] * rsqrtf(st[DIM + d1] * invN - mu1 * mu1 + 1e-5f);
    float b0 = beta[d0], b1 = beta[d1];
    for (int n = wv; n < NP; n += nw) {
      float2 v = *(float2*)(xp + (size_t)n * DIM + d0);
      float y0 = fmaf(v.x - mu0, g0, b0);
      float y1 = fmaf(v.y - mu1, g1, b1);
      float p = y0 * y0 + y1 * y1;
#pragma unroll
      for (int off = 32; off; off >>= 1) p += __shfl_xor(p, off, 64);
      float r = rsqrtf(p + 1e-12f);
      float2 o; o.x = y0 * r; o.y = y1 * r;
      *(float2*)(xp + (size_t)n * DIM + d0) = o;
    }
  }
  {
    float invN = 1.f / (float)NA;
    float mu0 = st[2 * DIM + d0] * invN, mu1 = st[2 * DIM + d1] * invN;
    float g0 = gamma[d0] * rsqrtf(st[3 * DIM + d0] * invN - mu0 * mu0 + 1e-5f);
    float g1 = gamma[d1] * rsqrtf(st[3 * DIM + d1] * invN - mu1 * mu1 + 1e-5f);
    float b0 = beta[d0], b1 = beta[d1];
    for (int n = wv; n < NA; n += nw) {
      float2 v = *(float2*)(xa + (size_t)n * DIM + d0);
      float y0 = fmaf(v.x - mu0, g0, b0);
      float y1 = fmaf(v.y - mu1, g1, b1);
      float p = y0 * y0 + y1 * y1;
#pragma unroll
      for (int off = 32; off; off >>= 1) p += __shfl_xor(p, off, 64);
      float r = rsqrtf(p + 1e-12f);
      float2 o; o.x = y0 * r; o.y = y1 * r;
      *(float2*)(xa + (size_t)n * DIM + d0) = o;
    }
  }
}

extern "C" void kernel_launch(void* const* d_in, const int* in_sizes, int n_in,
                              void* d_out, int out_size, void* d_ws, size_t ws_size,
                              hipStream_t stream) {
  const float* h_paper  = (const float*)d_in[0];
  const float* h_author = (const float*)d_in[1];
  const float* W_r1 = (const float*)d_in[2];
  const float* W_r2 = (const float*)d_in[3];
  const float* W_r3 = (const float*)d_in[4];
  const float* att_W = (const float*)d_in[5];
  const float* att_b = (const float*)d_in[6];
  const float* att_q = (const float*)d_in[7];
  const float* bn_g = (const float*)d_in[8];
  const float* bn_b = (const float*)d_in[9];
  const int* src_r1 = (const int*)d_in[10];
  const int* dst_r1 = (const int*)d_in[11];
  const int* src_r2 = (const int*)d_in[12];
  const int* dst_r2 = (const int*)d_in[13];
  const int* src_r3 = (const int*)d_in[14];
  const int* dst_r3 = (const int*)d_in[15];

  int NP = in_sizes[0] / DIM;
  int NA = in_sizes[1] / DIM;
  int E1 = in_sizes[10], E2 = in_sizes[12], E3 = in_sizes[14];
  int NM = NP > NA ? NP : NA;
  int M = 3 * NM;                       // concatenated degree array length
  int B = (M + 2047) / 2048;            // scan partial blocks (<=256)

  char* ws = (char*)d_ws;
  size_t off = 0;
  float* m_buf = (float*)(ws + off); off += align256((size_t)NM * DIM * 4);
  float* z2    = (float*)(ws + off); off += align256((size_t)NP * DIM * 4);
  int* col     = (int*)(ws + off);   off += align256(((size_t)E1 + E2 + E3) * 4);
  int* rp      = (int*)(ws + off);   off += align256(((size_t)M + 1) * 4);
  int* cur     = (int*)(ws + off);   off += align256((size_t)M * 4);
  int* part    = (int*)(ws + off);   off += align256(256 * 4);
  size_t zoff = off;  // zero-initialized region
  int* din     = (int*)(ws + off);   off += (size_t)M * 4;
  int* dout    = (int*)(ws + off);   off += (size_t)M * 4;
  float* wsum  = (float*)(ws + off); off += 2 * 4;
  float* stats = (float*)(ws + off); off += 4 * DIM * 4;
  size_t zbytes = off - zoff;

  float* xp = (float*)d_out;                       // papers (z_p1 staging)
  float* xa = (float*)d_out + (size_t)NP * DIM;    // authors (z_a1 staging)

  hipMemsetAsync(ws + zoff, 0, zbytes, stream);

  k_deg3<<<2048, 256, 0, stream>>>(src_r1, dst_r1, E1, src_r2, dst_r2, E2,
                                   src_r3, dst_r3, E3, dout, din, NM);

  k_scan1<<<B, 256, 0, stream>>>(din, part, M);
  k_scan2<<<1, 256, 0, stream>>>(part, B, rp, M);
  k_scan3<<<B, 256, 0, stream>>>(din, part, rp, cur, M);

  k_fill3<<<2048, 256, 0, stream>>>(src_r1, dst_r1, E1, src_r2, dst_r2, E2,
                                    src_r3, dst_r3, E3, cur, col, NM);

  // r1: author -> paper (z_p1 -> xp)
  k_gemm<<<512, 512, 0, stream>>>(h_author, W_r1, dout, m_buf, NA);
  k_pull<<<2048, 256, 0, stream>>>(m_buf, rp, col, xp, NP);
  // r2: paper -> paper (z_p2 -> ws)
  k_gemm<<<512, 512, 0, stream>>>(h_paper, W_r2, dout + NM, m_buf, NP);
  k_pull<<<2048, 256, 0, stream>>>(m_buf, rp + NM, col, z2, NP);
  // r3: author -> author (z_a1 -> xa; softmax over 1 relation == identity)
  k_gemm<<<512, 512, 0, stream>>>(h_author, W_r3, dout + 2 * NM, m_buf, NA);
  k_pull<<<2048, 256, 0, stream>>>(m_buf, rp + 2 * NM, col, xa, NA);

  // semantic attention (papers)
  k_att<<<512, 512, 0, stream>>>(xp, z2, att_W, att_b, att_q, wsum, NP);
  k_combine<<<2048, 256, 0, stream>>>(xp, z2, wsum, 1.0f / (float)NP, NP * DIM / 4);

  // BatchNorm stats + apply + row L2 for both outputs
  k_stats2<<<1024, 128, 0, stream>>>(xp, xa, NP, NA, stats);
  k_post2<<<2048, 256, 0, stream>>>(xp, xa, stats, bn_g, bn_b, NP, NA);
}